// Round 6
// baseline (475.407 us; speedup 1.0000x reference)
//
#include <hip/hip_runtime.h>

#define N_NODES 100000
#define N_EDGES 1600000
#define F 128
#define H 16
#define C 40
#define NH (N_NODES * H)
#define NPAD 102400        // padded node count for replica arrays
#define NREP 16            // histogram replicas
#define SCAN_BLOCKS 391    // ceil(N_NODES / 256)

// ---------------- zero-fill -------------------------------------------------
__global__ __launch_bounds__(256) void k_zero(int* __restrict__ p, int n) {
  int t = blockIdx.x * 256 + threadIdx.x;
  if (t < n) p[t] = 0;
}

// ---------------- layer-1 projection: xn1 = x@Wn1, y1 = x@Ws1 + b1 ----------
// 64 nodes per block, 4 waves; wave selects (matrix, col-half); weights via
// wave-uniform scalar loads; x broadcast from LDS (pad 129 -> free 2-way).
__global__ __launch_bounds__(256) void k_proj1(
    const float* __restrict__ x, const float* __restrict__ wn,
    const float* __restrict__ wsf, const float* __restrict__ b,
    float* __restrict__ xn1, float* __restrict__ y1) {
  __shared__ float xs[64 * 129];
  const int tid = threadIdx.x;
  const int node0 = blockIdx.x * 64;
  for (int i = tid; i < 64 * 32; i += 256) {
    int r = i >> 5, cv = i & 31;
    int n = node0 + r;
    float4 v = make_float4(0.f, 0.f, 0.f, 0.f);
    if (n < N_NODES) v = ((const float4*)x)[(size_t)n * 32 + cv];
    float* dp = &xs[r * 129 + cv * 4];
    dp[0] = v.x; dp[1] = v.y; dp[2] = v.z; dp[3] = v.w;
  }
  __syncthreads();

  const int wave = __builtin_amdgcn_readfirstlane(tid >> 6);
  const int lane = tid & 63;
  const int n = node0 + lane;
  const float* wmat = (wave < 2) ? wn : wsf;
  const int c0 = (wave & 1) * 8;

  float acc[8] = {0.f, 0.f, 0.f, 0.f, 0.f, 0.f, 0.f, 0.f};
  const float* xrow = &xs[lane * 129];
#pragma unroll 8
  for (int k = 0; k < F; ++k) {
    float xv = xrow[k];
    const float* wr = wmat + k * H + c0;
#pragma unroll
    for (int j = 0; j < 8; ++j) acc[j] += xv * wr[j];
  }
  if (n < N_NODES) {
    if (wave < 2) {
#pragma unroll
      for (int j = 0; j < 8; ++j) xn1[n * H + c0 + j] = acc[j];
    } else {
#pragma unroll
      for (int j = 0; j < 8; ++j) y1[n * H + c0 + j] = acc[j] + b[c0 + j];
    }
  }
}

// ---------------- degree histogram, 16-way replicated (int) -----------------
__global__ __launch_bounds__(256) void k_deghist(const int* __restrict__ dst,
                                                 int* __restrict__ degr) {
  int t = blockIdx.x * 256 + threadIdx.x;
  if (t >= N_EDGES) return;
  int rep = blockIdx.x & (NREP - 1);
  atomicAdd(&degr[rep * NPAD + dst[t]], 1);
}

// ---------------- scan step 1: per-node degree + block-level exclusive scan -
__global__ __launch_bounds__(256) void k_scan1(const int* __restrict__ degr,
                                               int* __restrict__ rs,
                                               int* __restrict__ bsum) {
  __shared__ int sh[256];
  const int tid = threadIdx.x;
  const int d = blockIdx.x * 256 + tid;
  int v = 0;
  if (d < N_NODES) {
#pragma unroll
    for (int r = 0; r < NREP; ++r) v += degr[r * NPAD + d];
  }
  sh[tid] = v;
  __syncthreads();
  for (int off = 1; off < 256; off <<= 1) {
    int t2 = (tid >= off) ? sh[tid - off] : 0;
    __syncthreads();
    sh[tid] += t2;
    __syncthreads();
  }
  rs[d] = sh[tid] - v;  // exclusive within block
  if (tid == 255) bsum[blockIdx.x] = sh[255];
}

// ---------------- scan step 2: scan the block sums (single block) -----------
__global__ __launch_bounds__(512) void k_scan2(int* __restrict__ bsum) {
  __shared__ int sh[512];
  const int tid = threadIdx.x;
  int v = (tid < SCAN_BLOCKS) ? bsum[tid] : 0;
  sh[tid] = v;
  __syncthreads();
  for (int off = 1; off < 512; off <<= 1) {
    int t2 = (tid >= off) ? sh[tid - off] : 0;
    __syncthreads();
    sh[tid] += t2;
    __syncthreads();
  }
  bsum[tid] = sh[tid] - v;  // exclusive
}

// -------- scan step 3: finalize row_start; turn histogram into cursors ------
__global__ __launch_bounds__(256) void k_scan3(int* __restrict__ degr,
                                               int* __restrict__ rs,
                                               const int* __restrict__ bsum) {
  const int d = blockIdx.x * 256 + threadIdx.x;
  if (d >= N_NODES) return;
  const int base = rs[d] + bsum[d >> 8];
  rs[d] = base;
  int run = base;
#pragma unroll
  for (int r = 0; r < NREP; ++r) {
    int c = degr[r * NPAD + d];
    degr[r * NPAD + d] = run;  // cursor base for (rep r, node d)
    run += c;
  }
  if (d == 0) rs[N_NODES] = N_EDGES;
}

// ---------------- placement: sorted_src grouped by dst ----------------------
// Scattered 4B plain stores are pathological (17x write amplification,
// partial-line writebacks across XCDs). atomicExch uses the word-granular
// write-through path measured at 127 ops/cycle.
__global__ __launch_bounds__(256) void k_place(const int* __restrict__ src,
                                               const int* __restrict__ dst,
                                               int* __restrict__ degr,
                                               int* __restrict__ sorted) {
  int t = blockIdx.x * 256 + threadIdx.x;
  if (t >= N_EDGES) return;
  int rep = blockIdx.x & (NREP - 1);  // must match k_deghist
  int d = dst[t];
  int pos = atomicAdd(&degr[rep * NPAD + d], 1);
  atomicExch(&sorted[pos], src[t]);
}

// -------- gather1 + hidden: h = relu(y1 + mean(xn1[neighbors])) in place ----
// One wave per node: lanes = 4 edge-slots x 16 feats. 4 independent row
// loads in flight per iteration; shfl_xor(16/32) reduces the 4 partials.
__global__ __launch_bounds__(256) void k_gather1(
    const float* __restrict__ xn1, const int* __restrict__ sorted,
    const int* __restrict__ rs, float* __restrict__ y1h) {
  const int tid = threadIdx.x;
  const int n = blockIdx.x * 4 + (tid >> 6);  // 25000 * 4 == 100000
  const int lane = tid & 63;
  const int eo = lane >> 4;
  const int j = lane & 15;
  const int e0 = rs[n], e1 = rs[n + 1];
  float sum = 0.f;
  for (int e = e0 + eo; e < e1; e += 4) sum += xn1[sorted[e] * H + j];
  sum += __shfl_xor(sum, 16);
  sum += __shfl_xor(sum, 32);
  if (eo == 0) {
    const float r = 1.f / fmaxf((float)(e1 - e0), 1.f);
    const int idx = n * H + j;
    y1h[idx] = fmaxf(y1h[idx] + sum * r, 0.f);
  }
}

// -------- gather2 + layer-2 projection: out = h@Ws2 + mean2@Wn2 + b2 --------
// 1024 threads = 16 waves = 16 nodes per block; wave-per-node gather, then
// LDS roundtrip into a 16x40 output matmul.
__global__ __launch_bounds__(1024) void k_gather2out(
    const float* __restrict__ h, const int* __restrict__ sorted,
    const int* __restrict__ rs, const float* __restrict__ wn,
    const float* __restrict__ wsf, const float* __restrict__ b,
    float* __restrict__ out) {
  __shared__ float wn_s[H * C];
  __shared__ float ws_s[H * C];
  __shared__ float b_s[C];
  __shared__ float hv[16][H + 1];
  __shared__ float sm[16][H + 1];
  const int tid = threadIdx.x;
  for (int i = tid; i < H * C; i += 1024) {
    wn_s[i] = wn[i];
    ws_s[i] = wsf[i];
  }
  if (tid < C) b_s[tid] = b[tid];

  const int nl = tid >> 6;  // wave = local node 0..15
  const int lane = tid & 63;
  const int eo = lane >> 4;
  const int j = lane & 15;
  const int n = blockIdx.x * 16 + nl;  // 6250 * 16 == 100000
  const int e0 = rs[n], e1 = rs[n + 1];
  float sum = 0.f;
  for (int e = e0 + eo; e < e1; e += 4) sum += h[sorted[e] * H + j];
  sum += __shfl_xor(sum, 16);
  sum += __shfl_xor(sum, 32);
  if (eo == 0) {
    const float r = 1.f / fmaxf((float)(e1 - e0), 1.f);
    sm[nl][j] = sum * r;
    hv[nl][j] = h[n * H + j];
  }
  __syncthreads();

  for (int i = tid; i < 16 * C; i += 1024) {
    int n2 = i / C, c = i % C;
    float acc = b_s[c];
#pragma unroll
    for (int jj = 0; jj < H; ++jj)
      acc += hv[n2][jj] * ws_s[jj * C + c] + sm[n2][jj] * wn_s[jj * C + c];
    out[(blockIdx.x * 16 + n2) * C + c] = acc;
  }
}

extern "C" void kernel_launch(void* const* d_in, const int* in_sizes, int n_in,
                              void* d_out, int out_size, void* d_ws,
                              size_t ws_size, hipStream_t stream) {
  const float* x = (const float*)d_in[0];
  const int* src = (const int*)d_in[1];
  const int* dst = (const int*)d_in[2];
  const float* wn1 = (const float*)d_in[3];
  const float* ws1 = (const float*)d_in[4];
  const float* b1 = (const float*)d_in[5];
  const float* wn2 = (const float*)d_in[6];
  const float* ws2 = (const float*)d_in[7];
  const float* b2 = (const float*)d_in[8];
  float* out = (float*)d_out;

  // d_out scratch (dead before k_gather2out writes out):
  //   xn1  [0, NH)                       6.4 MB
  //   degr [NH, NH + NREP*NPAD) as int   6.55 MB
  float* xn1 = out;
  int* degr = (int*)(out + NH);

  // ws (13.2 MB): sorted_src | y1h | row_start | block sums
  int* sorted = (int*)d_ws;                 // N_EDGES ints
  float* y1h = (float*)d_ws + N_EDGES;      // NH floats
  int* rs = (int*)d_ws + N_EDGES + NH;      // N_NODES+1 (padded to 100352)
  int* bsum = rs + 100352;                  // 512 ints

  k_zero<<<(NREP * NPAD) / 256, 256, 0, stream>>>(degr, NREP * NPAD);
  k_proj1<<<(N_NODES + 63) / 64, 256, 0, stream>>>(x, wn1, ws1, b1, xn1, y1h);
  k_deghist<<<N_EDGES / 256, 256, 0, stream>>>(dst, degr);
  k_scan1<<<SCAN_BLOCKS, 256, 0, stream>>>(degr, rs, bsum);
  k_scan2<<<1, 512, 0, stream>>>(bsum);
  k_scan3<<<SCAN_BLOCKS, 256, 0, stream>>>(degr, rs, bsum);
  k_place<<<N_EDGES / 256, 256, 0, stream>>>(src, dst, degr, sorted);
  k_gather1<<<N_NODES / 4, 256, 0, stream>>>(xn1, sorted, rs, y1h);
  k_gather2out<<<N_NODES / 16, 1024, 0, stream>>>(y1h, sorted, rs, wn2, ws2,
                                                  b2, out);
}

// Round 8
// 406.181 us; speedup vs baseline: 1.1704x; 1.1704x over previous
//
#include <hip/hip_runtime.h>

#define N_NODES 100000
#define N_EDGES 1600000
#define F 128
#define H 16
#define C 40
#define NH (N_NODES * H)
#define NPAD 102400  // padded node count for replica arrays
#define NREP 16      // deg histogram replicas

// ---------------- zero-fill two regions -------------------------------------
__global__ __launch_bounds__(256) void k_zero2(float* __restrict__ a, int na,
                                               float* __restrict__ b, int nb) {
  int t = blockIdx.x * 256 + threadIdx.x;
  if (t < na) a[t] = 0.0f;
  if (t < nb) b[t] = 0.0f;
}

// ---------------- layer-1 projection: xn1 = x@Wn1, y1 = x@Ws1 + b1 ----------
// 64 nodes per block, 4 waves; wave selects (matrix, col-half); weights via
// wave-uniform scalar loads; x broadcast from LDS (pad 129 -> free 2-way).
__global__ __launch_bounds__(256) void k_proj1(
    const float* __restrict__ x, const float* __restrict__ wn,
    const float* __restrict__ wsf, const float* __restrict__ b,
    float* __restrict__ xn1, float* __restrict__ y1) {
  __shared__ float xs[64 * 129];
  const int tid = threadIdx.x;
  const int node0 = blockIdx.x * 64;
  for (int i = tid; i < 64 * 32; i += 256) {
    int r = i >> 5, cv = i & 31;
    int n = node0 + r;
    float4 v = make_float4(0.f, 0.f, 0.f, 0.f);
    if (n < N_NODES) v = ((const float4*)x)[(size_t)n * 32 + cv];
    float* dp = &xs[r * 129 + cv * 4];
    dp[0] = v.x; dp[1] = v.y; dp[2] = v.z; dp[3] = v.w;
  }
  __syncthreads();

  const int wave = __builtin_amdgcn_readfirstlane(tid >> 6);
  const int lane = tid & 63;
  const int n = node0 + lane;
  const float* wmat = (wave < 2) ? wn : wsf;
  const int c0 = (wave & 1) * 8;

  float acc[8] = {0.f, 0.f, 0.f, 0.f, 0.f, 0.f, 0.f, 0.f};
  const float* xrow = &xs[lane * 129];
#pragma unroll 8
  for (int k = 0; k < F; ++k) {
    float xv = xrow[k];
    const float* wr = wmat + k * H + c0;
#pragma unroll
    for (int j = 0; j < 8; ++j) acc[j] += xv * wr[j];
  }
  if (n < N_NODES) {
    if (wave < 2) {
#pragma unroll
      for (int j = 0; j < 8; ++j) xn1[n * H + c0 + j] = acc[j];
    } else {
#pragma unroll
      for (int j = 0; j < 8; ++j) y1[n * H + c0 + j] = acc[j] + b[c0 + j];
    }
  }
}

// ------- degree histogram, 16-way replicated FLOAT (non-returning fp atomic
//         = the measured-fast memory-side path; scattered -> ~127 ops/cyc) ---
__global__ __launch_bounds__(256) void k_deghist(const int* __restrict__ dst,
                                                 float* __restrict__ degr) {
  int t = blockIdx.x * 256 + threadIdx.x;
  if (t >= N_EDGES) return;
  int rep = blockIdx.x & (NREP - 1);
  atomicAdd(&degr[rep * NPAD + dst[t]], 1.0f);
}

// ---------------- scatter-add 16-float rows: agg[dst] += v[src] -------------
// Thread per (edge, feat). Non-returning scalar fp32 atomics: measured at the
// 128-channel L2 atomic roofline (127 ops/cycle, 4 B/op write-through).
__global__ __launch_bounds__(256) void k_scatter(const float* __restrict__ v,
                                                 const int* __restrict__ src,
                                                 const int* __restrict__ dst,
                                                 float* __restrict__ agg) {
  int t = blockIdx.x * 256 + threadIdx.x;
  if (t >= N_EDGES * H) return;
  int e = t >> 4;
  int j = t & 15;
  int s = src[e];
  int d = dst[e];
  atomicAdd(&agg[d * H + j], v[s * H + j]);
}

// ------- h = relu(y1 + agg/deg); deg = shfl-reduced replicas;
//         re-zero agg for layer 2; lane j==0 stores rdeg ---------------------
__global__ __launch_bounds__(256) void k_hidden(float* __restrict__ y1h,
                                                float* __restrict__ agg,
                                                const float* __restrict__ degr,
                                                float* __restrict__ rdeg) {
  int t = blockIdx.x * 256 + threadIdx.x;
  if (t >= NH) return;
  int n = t >> 4;
  int j = t & 15;
  // lanes j=0..15 of node n each hold one replica; butterfly-sum them
  float d = degr[j * NPAD + n];
  d += __shfl_xor(d, 1);
  d += __shfl_xor(d, 2);
  d += __shfl_xor(d, 4);
  d += __shfl_xor(d, 8);
  float r = 1.0f / fmaxf(d, 1.0f);
  float v = y1h[t] + agg[t] * r;
  y1h[t] = fmaxf(v, 0.f);
  agg[t] = 0.f;
  if (j == 0) rdeg[n] = r;
}

// ---------------- layer-2: out = h@Ws2 + (agg2*rdeg)@Wn2 + b2 ---------------
// 8 nodes per block, 40 threads per node (block = 320 = 5 waves).
__global__ __launch_bounds__(320) void k_out(
    const float* __restrict__ h, const float* __restrict__ agg2,
    const float* __restrict__ rdeg, const float* __restrict__ wn,
    const float* __restrict__ wsf, const float* __restrict__ b,
    float* __restrict__ out) {
  __shared__ float wn_s[H * C];
  __shared__ float ws_s[H * C];
  __shared__ float b_s[C];
  const int tid = threadIdx.x;
  for (int i = tid; i < H * C; i += 320) {
    wn_s[i] = wn[i];
    ws_s[i] = wsf[i];
  }
  if (tid < C) b_s[tid] = b[tid];
  __syncthreads();
  const int nl = tid / C;
  const int c = tid % C;
  const int n = blockIdx.x * 8 + nl;
  if (n >= N_NODES) return;
  const float rd = rdeg[n];
  float acc = b_s[c];
#pragma unroll
  for (int j = 0; j < H; ++j) {
    float hv = h[n * H + j];
    float mv = agg2[n * H + j] * rd;
    acc += hv * ws_s[j * C + c] + mv * wn_s[j * C + c];
  }
  out[n * C + c] = acc;
}

extern "C" void kernel_launch(void* const* d_in, const int* in_sizes, int n_in,
                              void* d_out, int out_size, void* d_ws,
                              size_t ws_size, hipStream_t stream) {
  const float* x = (const float*)d_in[0];
  const int* src = (const int*)d_in[1];
  const int* dst = (const int*)d_in[2];
  const float* wn1 = (const float*)d_in[3];
  const float* ws1 = (const float*)d_in[4];
  const float* b1 = (const float*)d_in[5];
  const float* wn2 = (const float*)d_in[6];
  const float* ws2 = (const float*)d_in[7];
  const float* b2 = (const float*)d_in[8];
  float* out = (float*)d_out;

  // d_out scratch (4M floats; all consumed before k_out writes):
  //   xn1  [0, NH)                      6.4 MB
  //   degr [NH, NH + NREP*NPAD)         6.55 MB  (ends at 3.24M < 4M)
  float* xn1 = out;
  float* degr = out + NH;

  // ws (13.2 MB, verified fits): agg[NH] | y1h[NH] | rdeg[NPAD]
  float* wsp = (float*)d_ws;
  float* agg = wsp;
  float* y1h = agg + NH;
  float* rdeg = y1h + NH;

  const int ndeg = NREP * NPAD;  // 1.6384M
  k_zero2<<<(ndeg + 255) / 256, 256, 0, stream>>>(agg, NH, degr, ndeg);
  k_proj1<<<(N_NODES + 63) / 64, 256, 0, stream>>>(x, wn1, ws1, b1, xn1, y1h);
  k_deghist<<<N_EDGES / 256, 256, 0, stream>>>(dst, degr);
  k_scatter<<<(N_EDGES * H) / 256, 256, 0, stream>>>(xn1, src, dst, agg);
  k_hidden<<<NH / 256, 256, 0, stream>>>(y1h, agg, degr, rdeg);
  k_scatter<<<(N_EDGES * H) / 256, 256, 0, stream>>>(y1h, src, dst, agg);
  k_out<<<(N_NODES + 7) / 8, 320, 0, stream>>>(y1h, agg, rdeg, wn2, ws2, b2,
                                               out);
}